// Round 5
// baseline (1878.058 us; speedup 1.0000x reference)
//
#include <hip/hip_runtime.h>
#include <hip/hip_bf16.h>

#define NPB 16  // nodes per block in GEMM

__device__ __forceinline__ float b2f(__hip_bfloat16 v) { return __bfloat162float(v); }
// float-typed harness input that may be fp32 or bf16 (dt[0] selects)
__device__ __forceinline__ float ldf(const void* p, long i, int f32) {
    return f32 ? ((const float*)p)[i] : b2f(((const __hip_bfloat16*)p)[i]);
}
// integer harness input that may be int32 or little-endian int64 (<2^31) (dt[1] selects)
__device__ __forceinline__ int ldi(const int* p, long i, int i32) {
    return i32 ? p[i] : p[2 * i];
}

// ---------------- zero a float region (grid-stride) + zero dt ----------------
__global__ void zero_f(float* __restrict__ a, long n, int* __restrict__ dt)
{
    long i = (long)blockIdx.x * 256 + threadIdx.x;
    long stride = (long)gridDim.x * 256;
    for (; i < n; i += stride) a[i] = 0.f;
    if (blockIdx.x == 0 && threadIdx.x == 0 && dt) { dt[0] = 0; dt[1] = 0; }
}

// failure-gated fp32 code write (used for ws-guard only; runs unconditionally when guard trips)
__global__ void fail_stamp(float* __restrict__ out, float code)
{
    if (threadIdx.x == 0 && blockIdx.x == 0) out[0] = code;
}

// ---------------- dtype detection: dt[0]=1 -> fp32 floats ; dt[1]=1 -> int32 indices ----
__global__ void detect_kernel(const void* __restrict__ x, const int* __restrict__ ei,
                              int* __restrict__ dt, int E_)
{
    int t = threadIdx.x;
    const unsigned short* xb = (const unsigned short*)x;
    int f32 = 0;
    for (int i = t; i < 4096; i += 256) {
        int ex = (xb[i] >> 7) & 0xFF;   // bf16 exponent field
        if (ex > 140) f32 = 1;          // |v| > 2^13: impossible for bf16 N(0,1) data
    }
    if (f32) atomicOr(&dt[0], 1);
    int nz = 0;
    for (int i = t; i < 2048; i += 256) nz |= ei[2 * i + 1];  // int64 odd words are 0
    if (nz) atomicOr(&dt[1], 1);
}

// ---------------- K0: x_l = x@W_l + b_l ; x_r = x@W_r + b_r (fp32 acc, bf16 out) ----
__global__ __launch_bounds__(128) void gemm_xlr(
    const void* __restrict__ x,
    const void* __restrict__ Wl, const void* __restrict__ bl,
    const void* __restrict__ Wr, const void* __restrict__ br,
    const int* __restrict__ dt,
    __hip_bfloat16* __restrict__ xl, __hip_bfloat16* __restrict__ xr, int n)
{
    __shared__ float xs[NPB][128];
    int f32 = dt[0];
    int t = threadIdx.x;
    int n0 = blockIdx.x * NPB;
    for (int j = 0; j < NPB; ++j) {
        int node = n0 + j;
        xs[j][t] = (node < n) ? ldf(x, (long)node * 128 + t, f32) : 0.f;
    }
    __syncthreads();
    float accl[NPB], accr[NPB];
#pragma unroll
    for (int j = 0; j < NPB; ++j) { accl[j] = 0.f; accr[j] = 0.f; }
    for (int k = 0; k < 128; ++k) {
        float wl = ldf(Wl, k * 128 + t, f32);
        float wr = ldf(Wr, k * 128 + t, f32);
#pragma unroll
        for (int j = 0; j < NPB; ++j) {
            float xv = xs[j][k];
            accl[j] = fmaf(xv, wl, accl[j]);
            accr[j] = fmaf(xv, wr, accr[j]);
        }
    }
    float blv = ldf(bl, t, f32);
    float brv = ldf(br, t, f32);
    for (int j = 0; j < NPB; ++j) {
        int node = n0 + j;
        if (node < n) {
            xl[(long)node * 128 + t] = __float2bfloat16(accl[j] + blv);
            xr[(long)node * 128 + t] = __float2bfloat16(accr[j] + brv);
        }
    }
}

// ---------------- Pass A: per-(edge,head) logits -> ex (bf16) + denom atomicAdd ----
// block 256 = 64 edges x 4 heads.  No max-subtraction: |logit| <~ 30, exp fits fp32.
__global__ __launch_bounds__(256) void edge_logits(
    const int* __restrict__ ei, const int* __restrict__ dt,
    const void* __restrict__ ea, const void* __restrict__ We, const void* __restrict__ att,
    const __hip_bfloat16* __restrict__ xl, const __hip_bfloat16* __restrict__ xr,
    float* __restrict__ denom, __hip_bfloat16* __restrict__ ex_arr, int E_, int N_)
{
    __shared__ float We_s[16][128];
    __shared__ float att_s[128];
    __shared__ float ea_s[64][16];
    int t = threadIdx.x;
    int f32 = dt[0], i32 = dt[1];
    for (int i = t; i < 2048; i += 256) We_s[i >> 7][i & 127] = ldf(We, i, f32);
    if (t < 128) att_s[t] = ldf(att, t, f32);
    long e0 = (long)blockIdx.x * 64;
    for (int i = t; i < 1024; i += 256) {            // 64 edges x 16 attrs
        long e = e0 + (i >> 4);
        ea_s[i >> 4][i & 15] = (e < E_) ? ldf(ea, e * 16 + (i & 15), f32) : 0.f;
    }
    __syncthreads();
    int el = t >> 2, h = t & 3;
    long e = e0 + el;
    if (e >= E_) return;
    int s = ldi(ei, e, i32);
    int d = ldi(ei, E_ + e, i32);
    if ((unsigned)s >= (unsigned)N_ || (unsigned)d >= (unsigned)N_) return;
    float logit = 0.f;
    int cbase = h * 32;
    for (int cc = 0; cc < 32; ++cc) {
        int c = cbase + cc;
        float z = b2f(xl[(long)s * 128 + c]) + b2f(xr[(long)d * 128 + c]);
#pragma unroll
        for (int k = 0; k < 16; ++k) z = fmaf(ea_s[el][k], We_s[k][c], z);
        z = (z >= 0.f) ? z : 0.2f * z;
        logit = fmaf(z, att_s[c], logit);
    }
    float exv = __expf(logit);
    __hip_bfloat16 exb = __float2bfloat16(exv);
    ex_arr[e * 4 + h] = exb;
    atomicAdd(&denom[(long)d * 4 + h], b2f(exb));   // same rounded value as numerator
}

// ---------------- Pass B: per-(edge,channel) atomic aggregation ----------------
// block 256 = 2 edges x 128 channels.
__global__ __launch_bounds__(256) void edge_agg(
    const int* __restrict__ ei, const int* __restrict__ dt,
    const __hip_bfloat16* __restrict__ ex_arr, const __hip_bfloat16* __restrict__ xl,
    float* __restrict__ acc, int E_, int N_)
{
    int t = threadIdx.x;
    int el = t >> 7;
    int c = t & 127;
    long e = (long)blockIdx.x * 2 + el;
    if (e >= E_) return;
    int i32 = dt[1];
    int s = ldi(ei, e, i32);
    int d = ldi(ei, E_ + e, i32);
    if ((unsigned)s >= (unsigned)N_ || (unsigned)d >= (unsigned)N_) return;
    int h = c >> 5;
    float w = b2f(ex_arr[e * 4 + h]);
    float v = w * b2f(xl[(long)s * 128 + c]);
    atomicAdd(&acc[(long)d * 128 + c], v);
}

// ---------------- node: normalize + bias + LN + ReLU + residual -> FP32 out ----------------
__global__ __launch_bounds__(128) void node_final(
    const float* __restrict__ acc, const float* __restrict__ denom,
    const void* __restrict__ cb, const void* __restrict__ gamma,
    const void* __restrict__ beta, const void* __restrict__ x,
    const int* __restrict__ dt, float* __restrict__ out)
{
    __shared__ float red[128];
    int n = blockIdx.x, t = threadIdx.x, h = t >> 5;
    int f32 = dt[0];
    float outv = acc[(long)n * 128 + t] / (denom[(long)n * 4 + h] + 1e-16f) + ldf(cb, t, f32);

    red[t] = outv; __syncthreads();
    for (int s2 = 64; s2 > 0; s2 >>= 1) { if (t < s2) red[t] += red[t + s2]; __syncthreads(); }
    float mu = red[0] * (1.f / 128.f);
    __syncthreads();
    float dd = outv - mu;
    red[t] = dd * dd; __syncthreads();
    for (int s2 = 64; s2 > 0; s2 >>= 1) { if (t < s2) red[t] += red[t + s2]; __syncthreads(); }
    float var = red[0] * (1.f / 128.f);
    float y = dd * rsqrtf(var + 1e-5f) * ldf(gamma, t, f32) + ldf(beta, t, f32);
    y = fmaxf(y, 0.f);
    y += ldf(x, (long)n * 128 + t, f32);
    out[(long)n * 128 + t] = y;      // FP32 output (reference returns float32)
}

// ---------------- failure-gated post-check: did the edge stage contribute? ----------------
__global__ void check_kernel(const float* __restrict__ denom, const int* __restrict__ dt,
                             float* __restrict__ out, int N_)
{
    if (threadIdx.x != 0 || blockIdx.x != 0) return;
    float s = 0.f;
    int lim = (N_ < 1024) ? N_ : 1024;
    for (int i = 0; i < lim * 4; ++i) s += denom[i];
    if (!(s > 0.f) || !__builtin_isfinite(s))
        out[0] = 20000.f + 1000.f * dt[0] + 100.f * dt[1];   // decodable failure code
}

extern "C" void kernel_launch(void* const* d_in, const int* in_sizes, int n_in,
                              void* d_out, int out_size, void* d_ws, size_t ws_size,
                              hipStream_t stream) {
    const void* x     = d_in[0];
    const int*  ei    = (const int*)d_in[1];
    const void* ea    = d_in[2];
    const void* Wl    = d_in[3];
    const void* bl    = d_in[4];
    const void* Wr    = d_in[5];
    const void* br    = d_in[6];
    const void* We    = d_in[7];
    const void* att   = d_in[8];
    const void* cb    = d_in[9];
    const void* gamma = d_in[10];
    const void* beta  = d_in[11];
    float* out = (float*)d_out;

    const int N_ = in_sizes[0] / 128;   // 50000
    const int E_ = in_sizes[2] / 16;    // 1600000

    size_t need = 0;
    auto sz = [&](size_t b) { size_t r = need; need += (b + 255) & ~(size_t)255; return r; };
    size_t o_xl    = sz((size_t)N_ * 128 * 2);   // 12.8 MB bf16
    size_t o_xr    = sz((size_t)N_ * 128 * 2);   // 12.8 MB bf16
    size_t o_ex    = sz((size_t)E_ * 4 * 2);     // 12.8 MB bf16
    size_t o_acc   = sz((size_t)N_ * 128 * 4);   // 25.6 MB fp32
    size_t o_den   = sz((size_t)N_ * 4 * 4);     //  0.8 MB fp32
    size_t o_dt    = sz(256);

    if (need > ws_size) {  // workspace too small: decodable code 16384 and bail
        fail_stamp<<<1, 64, 0, stream>>>(out, 16384.f);
        return;
    }
    char* p = (char*)d_ws;
    __hip_bfloat16* xl     = (__hip_bfloat16*)(p + o_xl);
    __hip_bfloat16* xr     = (__hip_bfloat16*)(p + o_xr);
    __hip_bfloat16* ex_arr = (__hip_bfloat16*)(p + o_ex);
    float* acc             = (float*)(p + o_acc);
    float* denom           = (float*)(p + o_den);
    int*   dt              = (int*)(p + o_dt);

    zero_f<<<4096, 256, 0, stream>>>(acc, (long)N_ * 128, dt);
    zero_f<<<1024, 256, 0, stream>>>(denom, (long)N_ * 4, (int*)nullptr);
    detect_kernel<<<1, 256, 0, stream>>>(x, ei, dt, E_);
    gemm_xlr<<<(N_ + NPB - 1) / NPB, 128, 0, stream>>>(x, Wl, bl, Wr, br, dt, xl, xr, N_);
    edge_logits<<<(E_ + 63) / 64, 256, 0, stream>>>(ei, dt, ea, We, att, xl, xr,
                                                    denom, ex_arr, E_, N_);
    edge_agg<<<(E_ + 1) / 2, 256, 0, stream>>>(ei, dt, ex_arr, xl, acc, E_, N_);
    node_final<<<N_, 128, 0, stream>>>(acc, denom, cb, gamma, beta, x, dt, out);
    check_kernel<<<1, 64, 0, stream>>>(denom, dt, out, N_);
}

// Round 6
// 1102.041 us; speedup vs baseline: 1.7042x; 1.7042x over previous
//
#include <hip/hip_runtime.h>
#include <hip/hip_bf16.h>

#define NPB 16  // nodes per block in GEMM
#define EPB 64  // edges per block in fused edge kernel

__device__ __forceinline__ float b2f(__hip_bfloat16 v) { return __bfloat162float(v); }
// float-typed harness input that may be fp32 or bf16 (dt[0] selects)
__device__ __forceinline__ float ldf(const void* p, long i, int f32) {
    return f32 ? ((const float*)p)[i] : b2f(((const __hip_bfloat16*)p)[i]);
}
// integer harness input that may be int32 or little-endian int64 (<2^31) (dt[1] selects)
__device__ __forceinline__ int ldi(const int* p, long i, int i32) {
    return i32 ? p[i] : p[2 * i];
}

// ---------------- zero a float region (grid-stride) + zero dt ----------------
__global__ void zero_f(float* __restrict__ a, long n, int* __restrict__ dt)
{
    long i = (long)blockIdx.x * 256 + threadIdx.x;
    long stride = (long)gridDim.x * 256;
    for (; i < n; i += stride) a[i] = 0.f;
    if (blockIdx.x == 0 && threadIdx.x == 0 && dt) { dt[0] = 0; dt[1] = 0; }
}

// failure-gated fp32 code write (ws-guard only)
__global__ void fail_stamp(float* __restrict__ out, float code)
{
    if (threadIdx.x == 0 && blockIdx.x == 0) out[0] = code;
}

// ---------------- dtype detection: dt[0]=1 -> fp32 floats ; dt[1]=1 -> int32 indices ----
__global__ void detect_kernel(const void* __restrict__ x, const int* __restrict__ ei,
                              int* __restrict__ dt, int E_)
{
    int t = threadIdx.x;
    const unsigned short* xb = (const unsigned short*)x;
    int f32 = 0;
    for (int i = t; i < 4096; i += 256) {
        int ex = (xb[i] >> 7) & 0xFF;   // bf16 exponent field
        if (ex > 140) f32 = 1;          // |v| > 2^13: impossible for bf16 N(0,1) data
    }
    if (f32) atomicOr(&dt[0], 1);
    int nz = 0;
    for (int i = t; i < 2048; i += 256) nz |= ei[2 * i + 1];  // int64 odd words are 0
    if (nz) atomicOr(&dt[1], 1);
}

// ---------------- K0: x_l = x@W_l + b_l ; x_r = x@W_r + b_r (fp32 acc, bf16 out) ----
__global__ __launch_bounds__(128) void gemm_xlr(
    const void* __restrict__ x,
    const void* __restrict__ Wl, const void* __restrict__ bl,
    const void* __restrict__ Wr, const void* __restrict__ br,
    const int* __restrict__ dt,
    __hip_bfloat16* __restrict__ xl, __hip_bfloat16* __restrict__ xr, int n)
{
    __shared__ float xs[NPB][128];
    int f32 = dt[0];
    int t = threadIdx.x;
    int n0 = blockIdx.x * NPB;
    for (int j = 0; j < NPB; ++j) {
        int node = n0 + j;
        xs[j][t] = (node < n) ? ldf(x, (long)node * 128 + t, f32) : 0.f;
    }
    __syncthreads();
    float accl[NPB], accr[NPB];
#pragma unroll
    for (int j = 0; j < NPB; ++j) { accl[j] = 0.f; accr[j] = 0.f; }
    for (int k = 0; k < 128; ++k) {
        float wl = ldf(Wl, k * 128 + t, f32);
        float wr = ldf(Wr, k * 128 + t, f32);
#pragma unroll
        for (int j = 0; j < NPB; ++j) {
            float xv = xs[j][k];
            accl[j] = fmaf(xv, wl, accl[j]);
            accr[j] = fmaf(xv, wr, accr[j]);
        }
    }
    float blv = ldf(bl, t, f32);
    float brv = ldf(br, t, f32);
    for (int j = 0; j < NPB; ++j) {
        int node = n0 + j;
        if (node < n) {
            xl[(long)node * 128 + t] = __float2bfloat16(accl[j] + blv);
            xr[(long)node * 128 + t] = __float2bfloat16(accr[j] + brv);
        }
    }
}

// ---------------- fused edge kernel: logits + exp + denom/acc atomics ----------------
// 256 threads; lane = channel (c = t&127), 2 edges in flight per iteration.
// We_s[k][c]/att_s[c] stride-1 (conflict-free); ea_s/sd_s broadcast reads.
__global__ __launch_bounds__(256) void edge_fused(
    const int* __restrict__ ei, const int* __restrict__ dt,
    const void* __restrict__ ea, const void* __restrict__ We, const void* __restrict__ att,
    const __hip_bfloat16* __restrict__ xl, const __hip_bfloat16* __restrict__ xr,
    float* __restrict__ denom, float* __restrict__ acc, int E_, int N_)
{
    __shared__ float We_s[16][128];   // 8 KB
    __shared__ float att_s[128];
    __shared__ float ea_s[EPB][16];   // 4 KB
    __shared__ int   sd_s[2][EPB];
    int t = threadIdx.x;
    int f32 = dt[0], i32 = dt[1];
    for (int i = t; i < 2048; i += 256) We_s[i >> 7][i & 127] = ldf(We, i, f32);
    if (t < 128) att_s[t] = ldf(att, t, f32);
    long e0 = (long)blockIdx.x * EPB;
    for (int i = t; i < EPB * 16; i += 256) {          // stage edge_attr, coalesced
        long e = e0 + (i >> 4);
        ea_s[i >> 4][i & 15] = (e < E_) ? ldf(ea, e * 16 + (i & 15), f32) : 0.f;
    }
    if (t < EPB) {                                      // stage src
        long e = e0 + t;
        sd_s[0][t] = (e < E_) ? ldi(ei, e, i32) : -1;
    } else if (t < 2 * EPB) {                           // stage dst
        int u = t - EPB; long e = e0 + u;
        sd_s[1][u] = (e < E_) ? ldi(ei, E_ + e, i32) : -1;
    }
    __syncthreads();
    int half = t >> 7;        // which edge of the pair
    int c = t & 127;          // channel
    int h = c >> 5;           // head
    for (int it = 0; it < EPB / 2; ++it) {
        int le = it * 2 + half;
        long e = e0 + le;
        if (e >= E_) continue;
        int s = sd_s[0][le], d = sd_s[1][le];
        if ((unsigned)s >= (unsigned)N_ || (unsigned)d >= (unsigned)N_) continue;
        float xlv = b2f(xl[(long)s * 128 + c]);               // coalesced gather
        float z = xlv + b2f(xr[(long)d * 128 + c]);
#pragma unroll
        for (int k = 0; k < 16; ++k) z = fmaf(ea_s[le][k], We_s[k][c], z);
        z = (z >= 0.f) ? z : 0.2f * z;
        float v = z * att_s[c];
        for (int o = 16; o >= 1; o >>= 1) v += __shfl_xor(v, o, 32);  // all 32 lanes get sum
        float ex = __expf(v);                                  // no max-sub: |logit| small
        atomicAdd(&acc[(long)d * 128 + c], ex * xlv);          // message aggregation
        if ((c & 31) == 0) atomicAdd(&denom[(long)d * 4 + h], ex);
    }
}

// ---------------- node: normalize + bias + LN + ReLU + residual -> FP32 out ----------------
__global__ __launch_bounds__(128) void node_final(
    const float* __restrict__ acc, const float* __restrict__ denom,
    const void* __restrict__ cb, const void* __restrict__ gamma,
    const void* __restrict__ beta, const void* __restrict__ x,
    const int* __restrict__ dt, float* __restrict__ out)
{
    __shared__ float red[128];
    int n = blockIdx.x, t = threadIdx.x, h = t >> 5;
    int f32 = dt[0];
    float outv = acc[(long)n * 128 + t] / (denom[(long)n * 4 + h] + 1e-16f) + ldf(cb, t, f32);

    red[t] = outv; __syncthreads();
    for (int s2 = 64; s2 > 0; s2 >>= 1) { if (t < s2) red[t] += red[t + s2]; __syncthreads(); }
    float mu = red[0] * (1.f / 128.f);
    __syncthreads();
    float dd = outv - mu;
    red[t] = dd * dd; __syncthreads();
    for (int s2 = 64; s2 > 0; s2 >>= 1) { if (t < s2) red[t] += red[t + s2]; __syncthreads(); }
    float var = red[0] * (1.f / 128.f);
    float y = dd * rsqrtf(var + 1e-5f) * ldf(gamma, t, f32) + ldf(beta, t, f32);
    y = fmaxf(y, 0.f);
    y += ldf(x, (long)n * 128 + t, f32);
    out[(long)n * 128 + t] = y;      // FP32 output (reference returns float32)
}

extern "C" void kernel_launch(void* const* d_in, const int* in_sizes, int n_in,
                              void* d_out, int out_size, void* d_ws, size_t ws_size,
                              hipStream_t stream) {
    const void* x     = d_in[0];
    const int*  ei    = (const int*)d_in[1];
    const void* ea    = d_in[2];
    const void* Wl    = d_in[3];
    const void* bl    = d_in[4];
    const void* Wr    = d_in[5];
    const void* br    = d_in[6];
    const void* We    = d_in[7];
    const void* att   = d_in[8];
    const void* cb    = d_in[9];
    const void* gamma = d_in[10];
    const void* beta  = d_in[11];
    float* out = (float*)d_out;

    const int N_ = in_sizes[0] / 128;   // 50000
    const int E_ = in_sizes[2] / 16;    // 1600000

    size_t need = 0;
    auto sz = [&](size_t b) { size_t r = need; need += (b + 255) & ~(size_t)255; return r; };
    size_t o_xl    = sz((size_t)N_ * 128 * 2);   // 12.8 MB bf16
    size_t o_xr    = sz((size_t)N_ * 128 * 2);   // 12.8 MB bf16
    size_t o_acc   = sz((size_t)N_ * 128 * 4);   // 25.6 MB fp32
    size_t o_den   = sz((size_t)N_ * 4 * 4);     //  0.8 MB fp32
    size_t o_dt    = sz(256);

    if (need > ws_size) {  // workspace too small: decodable code and bail
        fail_stamp<<<1, 64, 0, stream>>>(out, 16384.f);
        return;
    }
    char* p = (char*)d_ws;
    __hip_bfloat16* xl     = (__hip_bfloat16*)(p + o_xl);
    __hip_bfloat16* xr     = (__hip_bfloat16*)(p + o_xr);
    float* acc             = (float*)(p + o_acc);
    float* denom           = (float*)(p + o_den);
    int*   dt              = (int*)(p + o_dt);

    zero_f<<<4096, 256, 0, stream>>>(acc, (long)N_ * 128, dt);
    zero_f<<<1024, 256, 0, stream>>>(denom, (long)N_ * 4, (int*)nullptr);
    detect_kernel<<<1, 256, 0, stream>>>(x, ei, dt, E_);
    gemm_xlr<<<(N_ + NPB - 1) / NPB, 128, 0, stream>>>(x, Wl, bl, Wr, br, dt, xl, xr, N_);
    edge_fused<<<(E_ + EPB - 1) / EPB, 256, 0, stream>>>(ei, dt, ea, We, att, xl, xr,
                                                         denom, acc, E_, N_);
    node_final<<<N_, 128, 0, stream>>>(acc, denom, cb, gamma, beta, x, dt, out);
}

// Round 7
// 1012.050 us; speedup vs baseline: 1.8557x; 1.0889x over previous
//
#include <hip/hip_runtime.h>
#include <hip/hip_bf16.h>

#define NPB 16  // nodes per block in GEMM
#define EPB 64  // edges per block in edge kernel

__device__ __forceinline__ float b2f(__hip_bfloat16 v) { return __bfloat162float(v); }
// float-typed harness input that may be fp32 or bf16 (dt[0] selects)
__device__ __forceinline__ float ldf(const void* p, long i, int f32) {
    return f32 ? ((const float*)p)[i] : b2f(((const __hip_bfloat16*)p)[i]);
}
// integer harness input that may be int32 or little-endian int64 (<2^31) (dt[1] selects)
__device__ __forceinline__ int ldi(const int* p, long i, int i32) {
    return i32 ? p[i] : p[2 * i];
}

// ---------------- zero ints (cnt) + dt ----------------
__global__ void zero_i(int* __restrict__ a, long n, int* __restrict__ dt)
{
    long i = (long)blockIdx.x * 256 + threadIdx.x;
    long stride = (long)gridDim.x * 256;
    for (; i < n; i += stride) a[i] = 0;
    if (blockIdx.x == 0 && threadIdx.x == 0 && dt) { dt[0] = 0; dt[1] = 0; }
}

// failure-gated fp32 code write (ws-guard only)
__global__ void fail_stamp(float* __restrict__ out, float code)
{
    if (threadIdx.x == 0 && blockIdx.x == 0) out[0] = code;
}

// ---------------- dtype detection: dt[0]=1 -> fp32 floats ; dt[1]=1 -> int32 indices ----
__global__ void detect_kernel(const void* __restrict__ x, const int* __restrict__ ei,
                              int* __restrict__ dt, int E_)
{
    int t = threadIdx.x;
    const unsigned short* xb = (const unsigned short*)x;
    int f32 = 0;
    for (int i = t; i < 4096; i += 256) {
        int ex = (xb[i] >> 7) & 0xFF;   // bf16 exponent field
        if (ex > 140) f32 = 1;          // |v| > 2^13: impossible for bf16 N(0,1) data
    }
    if (f32) atomicOr(&dt[0], 1);
    int nz = 0;
    for (int i = t; i < 2048; i += 256) nz |= ei[2 * i + 1];  // int64 odd words are 0
    if (nz) atomicOr(&dt[1], 1);
}

// ---------------- K0: x_l = x@W_l + b_l ; x_r = x@W_r + b_r (fp32 acc, bf16 out) ----
__global__ __launch_bounds__(128) void gemm_xlr(
    const void* __restrict__ x,
    const void* __restrict__ Wl, const void* __restrict__ bl,
    const void* __restrict__ Wr, const void* __restrict__ br,
    const int* __restrict__ dt,
    __hip_bfloat16* __restrict__ xl, __hip_bfloat16* __restrict__ xr, int n)
{
    __shared__ float xs[NPB][128];
    int f32 = dt[0];
    int t = threadIdx.x;
    int n0 = blockIdx.x * NPB;
    for (int j = 0; j < NPB; ++j) {
        int node = n0 + j;
        xs[j][t] = (node < n) ? ldf(x, (long)node * 128 + t, f32) : 0.f;
    }
    __syncthreads();
    float accl[NPB], accr[NPB];
#pragma unroll
    for (int j = 0; j < NPB; ++j) { accl[j] = 0.f; accr[j] = 0.f; }
    for (int k = 0; k < 128; ++k) {
        float wl = ldf(Wl, k * 128 + t, f32);
        float wr = ldf(Wr, k * 128 + t, f32);
#pragma unroll
        for (int j = 0; j < NPB; ++j) {
            float xv = xs[j][k];
            accl[j] = fmaf(xv, wl, accl[j]);
            accr[j] = fmaf(xv, wr, accr[j]);
        }
    }
    float blv = ldf(bl, t, f32);
    float brv = ldf(br, t, f32);
    for (int j = 0; j < NPB; ++j) {
        int node = n0 + j;
        if (node < n) {
            xl[(long)node * 128 + t] = __float2bfloat16(accl[j] + blv);
            xr[(long)node * 128 + t] = __float2bfloat16(accr[j] + brv);
        }
    }
}

// ---------------- histogram of dst ----------------
__global__ void hist_kernel(const int* __restrict__ ei, const int* __restrict__ dt,
                            int* __restrict__ cnt, int E_, int N_)
{
    long e = (long)blockIdx.x * 256 + threadIdx.x;
    if (e >= E_) return;
    int d = ldi(ei, E_ + e, dt[1]);
    if ((unsigned)d < (unsigned)N_) atomicAdd(&cnt[d], 1);
}

// ---------------- single-block scan: row_ptr (shifted inclusive) + fill (exclusive) ----
// Validated: R3 (this scan) and R4 (no scan) produced bit-identical outputs.
__global__ __launch_bounds__(1024) void scan_kernel(
    const int* __restrict__ cnt, int* __restrict__ row_ptr, int* __restrict__ fill, int n)
{
    __shared__ int wsum[16];
    __shared__ int carry_s;
    int t = threadIdx.x; int lane = t & 63; int w = t >> 6;
    if (t == 0) { carry_s = 0; row_ptr[0] = 0; }
    __syncthreads();
    for (int base = 0; base < n; base += 1024) {
        int idx = base + t;
        int v = (idx < n) ? cnt[idx] : 0;
        int s = v;
        for (int o = 1; o < 64; o <<= 1) { int u = __shfl_up(s, o, 64); if (lane >= o) s += u; }
        if (lane == 63) wsum[w] = s;
        __syncthreads();
        int carry = carry_s;
        if (w == 0) {
            int ws = (lane < 16) ? wsum[lane] : 0;
            for (int o = 1; o < 16; o <<= 1) { int u = __shfl_up(ws, o, 64); if (lane >= o) ws += u; }
            if (lane < 16) wsum[lane] = ws;
        }
        __syncthreads();
        int woff = (w > 0) ? wsum[w - 1] : 0;
        int incl = s + woff;
        if (idx < n) { row_ptr[idx + 1] = carry + incl; fill[idx] = carry + incl - v; }
        __syncthreads();
        if (t == 0) carry_s = carry + wsum[15];
        __syncthreads();
    }
}

// ---------------- edge kernel: logits -> ex, scattered into dst-sorted slots ----------------
// lane = channel (conflict-free LDS); 2 edges in flight; only int scatter atomics.
__global__ __launch_bounds__(256) void edge_csr(
    const int* __restrict__ ei, const int* __restrict__ dt,
    const void* __restrict__ ea, const void* __restrict__ We, const void* __restrict__ att,
    const __hip_bfloat16* __restrict__ xl, const __hip_bfloat16* __restrict__ xr,
    int* __restrict__ fill, int* __restrict__ src_sorted, float* __restrict__ lsorted,
    int E_, int N_)
{
    __shared__ float We_s[16][128];   // 8 KB
    __shared__ float att_s[128];
    __shared__ float ea_s[EPB][16];   // 4 KB
    __shared__ int   src_s[EPB], dst_s[EPB], pos_s[EPB];
    int t = threadIdx.x;
    int f32 = dt[0], i32 = dt[1];
    for (int i = t; i < 2048; i += 256) We_s[i >> 7][i & 127] = ldf(We, i, f32);
    if (t < 128) att_s[t] = ldf(att, t, f32);
    long e0 = (long)blockIdx.x * EPB;
    for (int i = t; i < EPB * 16; i += 256) {          // stage edge_attr, coalesced
        long e = e0 + (i >> 4);
        ea_s[i >> 4][i & 15] = (e < E_) ? ldf(ea, e * 16 + (i & 15), f32) : 0.f;
    }
    if (t < EPB) {
        long e = e0 + t;
        if (e < E_) {
            int s = ldi(ei, e, i32);
            int d = ldi(ei, E_ + e, i32);
            src_s[t] = s; dst_s[t] = d;
            pos_s[t] = ((unsigned)d < (unsigned)N_ && (unsigned)s < (unsigned)N_)
                         ? atomicAdd(&fill[d], 1) : -1;
        } else pos_s[t] = -1;
    }
    __syncthreads();
    int half = t >> 7;        // which edge of the pair
    int c = t & 127;          // channel
    int h = c >> 5;           // head
    for (int it = 0; it < EPB / 2; ++it) {
        int le = it * 2 + half;
        long e = e0 + le;
        if (e >= E_ || pos_s[le] < 0) continue;
        int s = src_s[le], d = dst_s[le];
        float z = b2f(xl[(long)s * 128 + c]) + b2f(xr[(long)d * 128 + c]);
#pragma unroll
        for (int k = 0; k < 16; ++k) z = fmaf(ea_s[le][k], We_s[k][c], z);
        z = (z >= 0.f) ? z : 0.2f * z;
        float v = z * att_s[c];
        for (int o = 16; o >= 1; o >>= 1) v += __shfl_xor(v, o, 32);  // head-sum in all lanes
        float ex = __expf(v);                          // no max-sub: |logit| small, fp32 safe
        long pos = pos_s[le];
        if ((c & 31) == 0) lsorted[pos * 4 + h] = ex;
        if (c == 0) src_sorted[pos] = s;
    }
}

// ---------------- node kernel: CSR aggregate + bias + LN + ReLU + residual -> fp32 out ----
__global__ __launch_bounds__(128) void node_csr(
    const int* __restrict__ row_ptr, const int* __restrict__ src_sorted,
    const float* __restrict__ lsorted, const __hip_bfloat16* __restrict__ xl,
    const void* __restrict__ cb, const void* __restrict__ gamma,
    const void* __restrict__ beta, const void* __restrict__ x,
    const int* __restrict__ dt, float* __restrict__ out)
{
    __shared__ float red[128];
    int n = blockIdx.x, t = threadIdx.x, h = t >> 5;
    int f32 = dt[0];
    int beg = row_ptr[n], end = row_ptr[n + 1];
    float acc = 0.f, den = 0.f;
    int i = beg;
    for (; i + 1 < end; i += 2) {      // unroll 2: two independent gathers in flight
        int s0 = src_sorted[i], s1 = src_sorted[i + 1];
        float e0v = lsorted[(long)i * 4 + h];
        float e1v = lsorted[(long)(i + 1) * 4 + h];
        float x0 = b2f(xl[(long)s0 * 128 + t]);
        float x1 = b2f(xl[(long)s1 * 128 + t]);
        acc = fmaf(e0v, x0, acc);
        acc = fmaf(e1v, x1, acc);
        den += e0v + e1v;
    }
    if (i < end) {
        int s0 = src_sorted[i];
        float e0v = lsorted[(long)i * 4 + h];
        acc = fmaf(e0v, b2f(xl[(long)s0 * 128 + t]), acc);
        den += e0v;
    }
    float outv = acc / (den + 1e-16f) + ldf(cb, t, f32);

    red[t] = outv; __syncthreads();
    for (int s2 = 64; s2 > 0; s2 >>= 1) { if (t < s2) red[t] += red[t + s2]; __syncthreads(); }
    float mu = red[0] * (1.f / 128.f);
    __syncthreads();
    float dd = outv - mu;
    red[t] = dd * dd; __syncthreads();
    for (int s2 = 64; s2 > 0; s2 >>= 1) { if (t < s2) red[t] += red[t + s2]; __syncthreads(); }
    float var = red[0] * (1.f / 128.f);
    float y = dd * rsqrtf(var + 1e-5f) * ldf(gamma, t, f32) + ldf(beta, t, f32);
    y = fmaxf(y, 0.f);
    y += ldf(x, (long)n * 128 + t, f32);
    out[(long)n * 128 + t] = y;      // fp32 output
}

extern "C" void kernel_launch(void* const* d_in, const int* in_sizes, int n_in,
                              void* d_out, int out_size, void* d_ws, size_t ws_size,
                              hipStream_t stream) {
    const void* x     = d_in[0];
    const int*  ei    = (const int*)d_in[1];
    const void* ea    = d_in[2];
    const void* Wl    = d_in[3];
    const void* bl    = d_in[4];
    const void* Wr    = d_in[5];
    const void* br    = d_in[6];
    const void* We    = d_in[7];
    const void* att   = d_in[8];
    const void* cb    = d_in[9];
    const void* gamma = d_in[10];
    const void* beta  = d_in[11];
    float* out = (float*)d_out;

    const int N_ = in_sizes[0] / 128;   // 50000
    const int E_ = in_sizes[2] / 16;    // 1600000

    size_t need = 0;
    auto sz = [&](size_t b) { size_t r = need; need += (b + 255) & ~(size_t)255; return r; };
    size_t o_xl   = sz((size_t)N_ * 128 * 2);   // 12.8 MB bf16
    size_t o_xr   = sz((size_t)N_ * 128 * 2);   // 12.8 MB bf16
    size_t o_cnt  = sz((size_t)N_ * 4);
    size_t o_row  = sz((size_t)(N_ + 1) * 4);
    size_t o_fill = sz((size_t)N_ * 4);
    size_t o_dt   = sz(256);
    size_t o_src  = sz((size_t)E_ * 4);          //  6.4 MB
    size_t o_lsr  = sz((size_t)E_ * 16);         // 25.6 MB

    if (need > ws_size) {
        fail_stamp<<<1, 64, 0, stream>>>(out, 16384.f);
        return;
    }
    char* p = (char*)d_ws;
    __hip_bfloat16* xl   = (__hip_bfloat16*)(p + o_xl);
    __hip_bfloat16* xr   = (__hip_bfloat16*)(p + o_xr);
    int*   cnt           = (int*)(p + o_cnt);
    int*   row_ptr       = (int*)(p + o_row);
    int*   fill          = (int*)(p + o_fill);
    int*   dt            = (int*)(p + o_dt);
    int*   src_sorted    = (int*)(p + o_src);
    float* lsorted       = (float*)(p + o_lsr);

    zero_i<<<256, 256, 0, stream>>>(cnt, N_, dt);
    detect_kernel<<<1, 256, 0, stream>>>(x, ei, dt, E_);
    gemm_xlr<<<(N_ + NPB - 1) / NPB, 128, 0, stream>>>(x, Wl, bl, Wr, br, dt, xl, xr, N_);
    hist_kernel<<<(E_ + 255) / 256, 256, 0, stream>>>(ei, dt, cnt, E_, N_);
    scan_kernel<<<1, 1024, 0, stream>>>(cnt, row_ptr, fill, N_);
    edge_csr<<<(E_ + EPB - 1) / EPB, 256, 0, stream>>>(ei, dt, ea, We, att, xl, xr,
                                                       fill, src_sorted, lsorted, E_, N_);
    node_csr<<<N_, 128, 0, stream>>>(row_ptr, src_sorted, lsorted, xl,
                                     cb, gamma, beta, x, dt, out);
}